// Round 11
// baseline (133.968 us; speedup 1.0000x reference)
//
#include <hip/hip_runtime.h>
#include <hip/hip_bf16.h>
#include <cstdint>
#include <cstddef>

#define SEQ   2048
#define BATCH 2
#define NROWS 4096          // BATCH*SEQ
#define EMB   1024
#define NHEAD 16
#define HD    64
#define KVBLK 64
#define NTG   16            // kv tiles per in-block group (1024 keys / 64)

typedef __attribute__((ext_vector_type(8))) short bf16x8;
typedef __attribute__((ext_vector_type(4))) float f32x4;
typedef __attribute__((ext_vector_type(16))) float f32x16;
typedef __attribute__((ext_vector_type(2))) int i32x2;
typedef __hip_bfloat16 bf16_t;

#define RAW_BAR() do { asm volatile("" ::: "memory"); __builtin_amdgcn_s_barrier(); asm volatile("" ::: "memory"); } while (0)
#define VMCNT6()  asm volatile("s_waitcnt vmcnt(6)" ::: "memory")
#define VMCNT0()  asm volatile("s_waitcnt vmcnt(0)" ::: "memory")
#define LGK0_SB() do { asm volatile("s_waitcnt lgkmcnt(0)" ::: "memory"); __builtin_amdgcn_sched_barrier(0); } while (0)

__device__ __forceinline__ int swz(int row, int cb) { return cb ^ ((row & 7) << 4); }

__device__ __forceinline__ void plswap(int a, int b, int& ra, int& rb) {
#if __has_builtin(__builtin_amdgcn_permlane32_swap)
  i32x2 r = __builtin_amdgcn_permlane32_swap(a, b, false, false);
  ra = r[0]; rb = r[1];
#else
  const int pa = __shfl_xor(a, 32), pb = __shfl_xor(b, 32);
  const bool lo = (threadIdx.x & 63) < 32;
  ra = lo ? a : pb;
  rb = lo ? pa : b;
#endif
}
__device__ __forceinline__ float pairmax32(float v) {
  int r0, r1;
  plswap(__float_as_int(v), __float_as_int(v), r0, r1);
  return fmaxf(__int_as_float(r0), __int_as_float(r1));
}
__device__ __forceinline__ float pairsum32(float v) {
  int r0, r1;
  plswap(__float_as_int(v), __float_as_int(v), r0, r1);
  return __int_as_float(r0) + __int_as_float(r1);
}

// ---------------- casts f32 -> bf16 (vectorized) ----------------
__global__ __launch_bounds__(256) void cast_f32_to_bf16(const float* __restrict__ in,
                                                        bf16_t* __restrict__ out, int n4) {
  int i = blockIdx.x * 256 + threadIdx.x;
  if (i >= n4) return;
  float4 v = reinterpret_cast<const float4*>(in)[i];
  union { ushort4 u; bf16_t h[4]; } o;
  o.h[0] = __float2bfloat16(v.x);
  o.h[1] = __float2bfloat16(v.y);
  o.h[2] = __float2bfloat16(v.z);
  o.h[3] = __float2bfloat16(v.w);
  reinterpret_cast<ushort4*>(out)[i] = o.u;
}

__global__ __launch_bounds__(256) void cast4_w(const float* __restrict__ a,
                                               const float* __restrict__ b,
                                               const float* __restrict__ c,
                                               const float* __restrict__ d,
                                               bf16_t* __restrict__ oa, bf16_t* __restrict__ ob,
                                               bf16_t* __restrict__ oc, bf16_t* __restrict__ od,
                                               int n4) {
  const int z = blockIdx.z;
  const float* in = (z == 0) ? a : (z == 1) ? b : (z == 2) ? c : d;
  bf16_t* out = (z == 0) ? oa : (z == 1) ? ob : (z == 2) ? oc : od;
  int i = blockIdx.x * 256 + threadIdx.x;
  if (i >= n4) return;
  float4 v = reinterpret_cast<const float4*>(in)[i];
  union { ushort4 u; bf16_t h[4]; } o;
  o.h[0] = __float2bfloat16(v.x);
  o.h[1] = __float2bfloat16(v.y);
  o.h[2] = __float2bfloat16(v.z);
  o.h[3] = __float2bfloat16(v.w);
  reinterpret_cast<ushort4*>(out)[i] = o.u;
}

// ---------------- 256x256 bf16 GEMM, BK=64, 8 waves, 4-phase pipeline -------
// One LDS allocation (128KB) at kernel scope; runtime epilogue mode (z==2 ->
// Vt-transposed write). Per phase: {ds_read issue + stage issue -> barrier ->
// lgkmcnt(0)+sched_barrier -> MFMA -> barrier} (m201 two-barrier discipline).
// Stage ledger per iter t (buf=t&1): P1 stages B(t+1,h1)->buf^1; P3 stages
// B(t+2,h0)->buf; P4 stages A(t+2,h0+h1)->buf, then vmcnt(6) (t<14; else
// vmcnt(0)) -> the 6 newest in-flight loads are exactly tile t+2's, so tile
// t+1 is resident before its first read. Swizzle: (row&7)<<4 byte-XOR, write
// side via inverse-swizzled global source (linear gload_lds dest), read side
// via same XOR (lr&7 == row&7 for all fragment reads).
__global__ __launch_bounds__(512) void gemm_qkv(const bf16_t* __restrict__ X,
                                                const bf16_t* __restrict__ Wq,
                                                const bf16_t* __restrict__ Wk,
                                                const bf16_t* __restrict__ Wv,
                                                bf16_t* __restrict__ Q,
                                                bf16_t* __restrict__ K,
                                                bf16_t* __restrict__ Vt) {
  __shared__ __align__(16) bf16_t LA[2][256 * 64];   // 64KB
  __shared__ __align__(16) bf16_t LB[2][256 * 64];   // 64KB
  const int z = blockIdx.z;
  const bf16_t* A = X;
  const bf16_t* W = (z == 0) ? Wq : (z == 1) ? Wk : Wv;
  bf16_t* Ob = (z == 0) ? Q : (z == 1) ? K : Vt;
  const bool vtmode = (z == 2);

  const int tid = threadIdx.x;
  const int lane = tid & 63;
  const int wv = tid >> 6;
  const int wm = wv >> 2, wn = wv & 3;      // 2x4 waves, each owns 128x64 of C
  const int brow = blockIdx.y * 256;
  const int bcol = blockIdx.x * 256;
  const int lr = lane & 15, lg = lane >> 4;

  f32x4 acc[8][4] = {};

  auto* LA3 = (__attribute__((address_space(3))) char*)&LA[0][0];
  auto* LB3 = (__attribute__((address_space(3))) char*)&LB[0][0];

  // staging: srow = tid>>3 (0..63), 16B chunk (tid&7); linear LDS dest,
  // inverse-swizzled global source (rule #21).
  const int srow = tid >> 3;
  const int sdst = (tid & 7) * 16;
  const int scol = (sdst ^ ((srow & 7) << 4)) >> 1;
  const bf16_t* Abase = A + (size_t)(brow + srow) * EMB + scol;
  const bf16_t* Wbase = W + (size_t)(bcol + srow) * EMB + scol;

  auto stageA = [&](int buf, int t, int h) {
#pragma unroll
    for (int i = 0; i < 2; ++i)
      __builtin_amdgcn_global_load_lds(
          (const __attribute__((address_space(1))) void*)(Abase + (size_t)(h * 128 + i * 64) * EMB + t * 64),
          (__attribute__((address_space(3))) void*)(LA3 + buf * 32768 + h * 16384 + i * 8192 + tid * 16),
          16, 0, 0);
  };
  auto stageB = [&](int buf, int t, int h) {
#pragma unroll
    for (int i = 0; i < 2; ++i)
      __builtin_amdgcn_global_load_lds(
          (const __attribute__((address_space(1))) void*)(Wbase + (size_t)(h * 128 + i * 64) * EMB + t * 64),
          (__attribute__((address_space(3))) void*)(LB3 + buf * 32768 + h * 16384 + i * 8192 + tid * 16),
          16, 0, 0);
  };

  // prologue: tile0 complete (8 loads, oldest), then tile1's B-h0 + A (6)
  stageA(0, 0, 0); stageA(0, 0, 1); stageB(0, 0, 0); stageB(0, 0, 1);
  stageB(1, 1, 0); stageA(1, 1, 0); stageA(1, 1, 1);
  VMCNT6();   // tile0's 8 landed; tile1's 6 in flight
  RAW_BAR();

  const char* LAc = (const char*)LA;
  const char* LBc = (const char*)LB;

  for (int t = 0; t < 16; ++t) {
    const int buf = t & 1;
    const char* La = LAc + buf * 32768;
    const char* Lb = LBc + buf * 32768;

    bf16x8 afr[4][2], b01[2][2], b23[2][2], afr2[4][2];

    // ---- P1: ds A(rows wm*128+0..63) + B(cols n0-1); stage B(t+1,h1)->buf^1
    if (t + 1 < 16) stageB(buf ^ 1, t + 1, 1);
#pragma unroll
    for (int m = 0; m < 4; ++m)
#pragma unroll
      for (int kk = 0; kk < 2; ++kk)
        afr[m][kk] = *reinterpret_cast<const bf16x8*>(
            La + (wm * 128 + m * 16 + lr) * 128 + swz(lr, kk * 64 + lg * 16));
#pragma unroll
    for (int n = 0; n < 2; ++n)
#pragma unroll
      for (int kk = 0; kk < 2; ++kk)
        b01[n][kk] = *reinterpret_cast<const bf16x8*>(
            Lb + (wn * 64 + n * 16 + lr) * 128 + swz(lr, kk * 64 + lg * 16));
    RAW_BAR();
    LGK0_SB();
    __builtin_amdgcn_s_setprio(1);
#pragma unroll
    for (int m = 0; m < 4; ++m)
#pragma unroll
      for (int n = 0; n < 2; ++n)
#pragma unroll
        for (int kk = 0; kk < 2; ++kk)
          acc[m][n] = __builtin_amdgcn_mfma_f32_16x16x32_bf16(afr[m][kk], b01[n][kk], acc[m][n], 0, 0, 0);
    __builtin_amdgcn_s_setprio(0);
    RAW_BAR();

    // ---- P2: ds B(cols n2-3); MFMA m0-3 x n2-3
#pragma unroll
    for (int n = 0; n < 2; ++n)
#pragma unroll
      for (int kk = 0; kk < 2; ++kk)
        b23[n][kk] = *reinterpret_cast<const bf16x8*>(
            Lb + (wn * 64 + 32 + n * 16 + lr) * 128 + swz(lr, kk * 64 + lg * 16));
    RAW_BAR();
    LGK0_SB();
    __builtin_amdgcn_s_setprio(1);
#pragma unroll
    for (int m = 0; m < 4; ++m)
#pragma unroll
      for (int n = 0; n < 2; ++n)
#pragma unroll
        for (int kk = 0; kk < 2; ++kk)
          acc[m][n + 2] = __builtin_amdgcn_mfma_f32_16x16x32_bf16(afr[m][kk], b23[n][kk], acc[m][n + 2], 0, 0, 0);
    __builtin_amdgcn_s_setprio(0);
    RAW_BAR();

    // ---- P3: ds A(rows wm*128+64..127); stage B(t+2,h0)->buf; MFMA m4-7 x n2-3
    if (t + 2 < 16) stageB(buf, t + 2, 0);
#pragma unroll
    for (int m = 0; m < 4; ++m)
#pragma unroll
      for (int kk = 0; kk < 2; ++kk)
        afr2[m][kk] = *reinterpret_cast<const bf16x8*>(
            La + (wm * 128 + 64 + m * 16 + lr) * 128 + swz(lr, kk * 64 + lg * 16));
    RAW_BAR();
    LGK0_SB();
    __builtin_amdgcn_s_setprio(1);
#pragma unroll
    for (int m = 0; m < 4; ++m)
#pragma unroll
      for (int n = 0; n < 2; ++n)
#pragma unroll
        for (int kk = 0; kk < 2; ++kk)
          acc[m + 4][n + 2] = __builtin_amdgcn_mfma_f32_16x16x32_bf16(afr2[m][kk], b23[n][kk], acc[m + 4][n + 2], 0, 0, 0);
    __builtin_amdgcn_s_setprio(0);
    RAW_BAR();

    // ---- P4: stage A(t+2)->buf; MFMA m4-7 x n0-1; counted vmcnt; barrier
    if (t + 2 < 16) { stageA(buf, t + 2, 0); stageA(buf, t + 2, 1); }
    __builtin_amdgcn_s_setprio(1);
#pragma unroll
    for (int m = 0; m < 4; ++m)
#pragma unroll
      for (int n = 0; n < 2; ++n)
#pragma unroll
        for (int kk = 0; kk < 2; ++kk)
          acc[m + 4][n] = __builtin_amdgcn_mfma_f32_16x16x32_bf16(afr2[m][kk], b01[n][kk], acc[m + 4][n], 0, 0, 0);
    __builtin_amdgcn_s_setprio(0);
    if (t < 14) { VMCNT6(); } else { VMCNT0(); }   // tail: <6 newer loads, must drain
    RAW_BAR();
  }

  const int r0 = brow + wm * 128;
  const int c0 = bcol + wn * 64;
#pragma unroll
  for (int m = 0; m < 8; ++m)
#pragma unroll
    for (int n = 0; n < 4; ++n) {
      if (vtmode) {
        const int row0 = r0 + m * 16 + lg * 4;
        const int col = c0 + n * 16 + lr;
        const size_t vt_row = (size_t)(row0 >> 11) * 1024 + col;
        const int s = row0 & 2047;
        union { uint2 u2; bf16_t h[4]; } pu;
#pragma unroll
        for (int r = 0; r < 4; ++r) pu.h[r] = __float2bfloat16(acc[m][n][r]);
        *reinterpret_cast<uint2*>(Ob + vt_row * SEQ + s) = pu.u2;
      } else {
#pragma unroll
        for (int r = 0; r < 4; ++r) {
          const int row = r0 + m * 16 + lg * 4 + r;
          const int col = c0 + n * 16 + lr;
          Ob[(size_t)row * EMB + col] = __float2bfloat16(acc[m][n][r]);
        }
      }
    }
}

// ---------------- 128x128 bf16 MFMA GEMM (m97 structure, 4 waves) ----------
// kept for gemm_out (256 blocks -> full CU coverage at 128 tile)
__global__ __launch_bounds__(256) void gemm_out(const bf16_t* __restrict__ Attn,
                                                const bf16_t* __restrict__ Wo,
                                                float* __restrict__ Y,
                                                const float* __restrict__ X) {
  __shared__ __align__(16) bf16_t As[128 * 32];
  __shared__ __align__(16) bf16_t Bs[128 * 32];
  const int tid = threadIdx.x;
  const int lane = tid & 63;
  const int wv = tid >> 6;
  const int wm = wv >> 1, wn = wv & 1;
  const int brow = blockIdx.y * 128;
  const int bcol = blockIdx.x * 128;
  const int lr = lane & 15, lg = lane >> 4;

  f32x4 acc[4][4] = {};

  auto* As3 = (__attribute__((address_space(3))) char*)As;
  auto* Bs3 = (__attribute__((address_space(3))) char*)Bs;

  for (int k0 = 0; k0 < EMB; k0 += 32) {
    __syncthreads();
#pragma unroll
    for (int i = 0; i < 2; ++i) {
      const int chunk = i * 256 + tid;
      const int row = chunk >> 2;
      const int kc = (chunk & 3) * 8;
      const bf16_t* ga = Attn + (size_t)(brow + row) * EMB + k0 + kc;
      const bf16_t* gb = Wo + (size_t)(bcol + row) * EMB + k0 + kc;
      __builtin_amdgcn_global_load_lds((const __attribute__((address_space(1))) void*)ga,
                                       (__attribute__((address_space(3))) void*)(As3 + chunk * 16),
                                       16, 0, 0);
      __builtin_amdgcn_global_load_lds((const __attribute__((address_space(1))) void*)gb,
                                       (__attribute__((address_space(3))) void*)(Bs3 + chunk * 16),
                                       16, 0, 0);
    }
    __syncthreads();

    bf16x8 af[4], bfr[4];
#pragma unroll
    for (int m = 0; m < 4; ++m)
      af[m] = *reinterpret_cast<const bf16x8*>(&As[(wm * 64 + m * 16 + lr) * 32 + lg * 8]);
#pragma unroll
    for (int n = 0; n < 4; ++n)
      bfr[n] = *reinterpret_cast<const bf16x8*>(&Bs[(wn * 64 + n * 16 + lr) * 32 + lg * 8]);
#pragma unroll
    for (int m = 0; m < 4; ++m)
#pragma unroll
      for (int n = 0; n < 4; ++n)
        acc[m][n] = __builtin_amdgcn_mfma_f32_16x16x32_bf16(af[m], bfr[n], acc[m][n], 0, 0, 0);
  }

  const int r0 = brow + wm * 64;
  const int c0 = bcol + wn * 64;
#pragma unroll
  for (int m = 0; m < 4; ++m)
#pragma unroll
    for (int n = 0; n < 4; ++n)
#pragma unroll
      for (int r = 0; r < 4; ++r) {
        const int row = r0 + m * 16 + lg * 4 + r;
        const int col = c0 + n * 16 + lr;
        const size_t idx = (size_t)row * EMB + col;
        Y[idx] = acc[m][n][r] + X[idx];
      }
}

// ---------------- flash attention: 8 waves, in-block KV-split x2 (round-9) --
__global__ __launch_bounds__(512, 4) void attn_kernel(const bf16_t* __restrict__ Q,
                                                      const bf16_t* __restrict__ K,
                                                      const bf16_t* __restrict__ Vt,
                                                      bf16_t* __restrict__ Oout) {
  __shared__ __align__(16) char L[65536];

  const int tid = threadIdx.x;
  const int lane = tid & 63;
  const int wv = tid >> 6;
  const int w = wv & 3;
  const int sg = wv >> 2;
  const int lq = lane & 31;
  const int lh = lane >> 5;

  const int f = blockIdx.x + 16 * blockIdx.y + 256 * blockIdx.z;
  const int ww = (f & 7) * 64 + (f >> 3);
  const int qb = ww & 15;
  const int h = (ww >> 4) & 15;
  const int b = ww >> 8;

  const size_t baseRow = (size_t)b * SEQ;
  const int hoff = h * HD;
  const int q0 = qb * 128 + w * 32;

  const float qscale = 0.125f * 1.44269504f;
  bf16x8 qf[4];
#pragma unroll
  for (int ks = 0; ks < 4; ++ks) {
    bf16x8 t = *reinterpret_cast<const bf16x8*>(
        &Q[(baseRow + q0 + lq) * EMB + hoff + ks * 16 + lh * 8]);
    union { bf16x8 v; bf16_t h[8]; } u;
    u.v = t;
#pragma unroll
    for (int e = 0; e < 8; ++e)
      u.h[e] = __float2bfloat16(__bfloat162float(u.h[e]) * qscale);
    qf[ks] = u.v;
  }

  f32x16 o0 = {}, o1 = {};
  float mrow = -1e30f, lrow = 0.f;

  auto* L3 = (__attribute__((address_space(3))) char*)L;
  const int gbase = sg * 32768;

  const int stid = tid & 255;
  const int srow = stid >> 3;
  const int scb = swz(srow, (stid & 7) * 16) >> 1;
  const bf16_t* kp = K + (baseRow + sg * 1024 + srow) * EMB + hoff + scb;
  const bf16_t* vp = Vt + ((size_t)(b * 1024 + hoff) + srow) * SEQ + sg * 1024 + scb;

  auto stage = [&](int buf) {
#pragma unroll
    for (int i = 0; i < 2; ++i) {
      const int c = i * 256 + stid;
      __builtin_amdgcn_global_load_lds(
          (const __attribute__((address_space(1))) void*)(kp + i * 32 * EMB),
          (__attribute__((address_space(3))) void*)(L3 + gbase + buf * 8192 + c * 16), 16, 0, 0);
      __builtin_amdgcn_global_load_lds(
          (const __attribute__((address_space(1))) void*)(vp + i * 32 * SEQ),
          (__attribute__((address_space(3))) void*)(L3 + gbase + 16384 + buf * 8192 + c * 16), 16, 0, 0);
    }
    kp += KVBLK * EMB;
    vp += KVBLK;
  };

  stage(0);
  __syncthreads();

  for (int t = 0; t < NTG; ++t) {
    const int cur = t & 1;
    if (t + 1 < NTG) stage(cur ^ 1);

    const char* Kb = (const char*)L + gbase + cur * 8192;
    const char* Vb = (const char*)L + gbase + 16384 + cur * 8192;

    f32x16 st0 = {}, st1 = {};
    __builtin_amdgcn_s_setprio(1);
#pragma unroll
    for (int ks = 0; ks < 4; ++ks) {
      bf16x8 kf0 = *reinterpret_cast<const bf16x8*>(Kb + lq * 128 + swz(lq, ks * 32 + lh * 16));
      st0 = __builtin_amdgcn_mfma_f32_32x32x16_bf16(kf0, qf[ks], st0, 0, 0, 0);
    }
#pragma unroll
    for (int ks = 0; ks < 4; ++ks) {
      bf16x8 kf1 = *reinterpret_cast<const bf16x8*>(Kb + (32 + lq) * 128 + swz(lq, ks * 32 + lh * 16));
      st1 = __builtin_amdgcn_mfma_f32_32x32x16_bf16(kf1, qf[ks], st1, 0, 0, 0);
    }
    __builtin_amdgcn_s_setprio(0);

    float mx = -1e30f;
#pragma unroll
    for (int r = 0; r < 16; ++r) mx = fmaxf(mx, st0[r]);
#pragma unroll
    for (int r = 0; r < 16; ++r) mx = fmaxf(mx, st1[r]);
    mx = pairmax32(mx);

    if (!__all(mx - mrow <= 8.f)) {
      const float mnew = fmaxf(mrow, mx);
      const float al = __builtin_amdgcn_exp2f(mrow - mnew);
      mrow = mnew;
      lrow *= al;
#pragma unroll
      for (int r = 0; r < 16; ++r) o0[r] *= al;
#pragma unroll
      for (int r = 0; r < 16; ++r) o1[r] *= al;
    }

#pragma unroll
    for (int r = 0; r < 16; ++r) st0[r] = __builtin_amdgcn_exp2f(st0[r] - mrow);
#pragma unroll
    for (int r = 0; r < 16; ++r) st1[r] = __builtin_amdgcn_exp2f(st1[r] - mrow);
    {
      float a0 = (st0[0] + st0[1]) + (st0[2] + st0[3]);
      float a1 = (st0[4] + st0[5]) + (st0[6] + st0[7]);
      float a2 = (st0[8] + st0[9]) + (st0[10] + st0[11]);
      float a3 = (st0[12] + st0[13]) + (st0[14] + st0[15]);
      float b0 = (st1[0] + st1[1]) + (st1[2] + st1[3]);
      float b1 = (st1[4] + st1[5]) + (st1[6] + st1[7]);
      float b2 = (st1[8] + st1[9]) + (st1[10] + st1[11]);
      float b3 = (st1[12] + st1[13]) + (st1[14] + st1[15]);
      lrow += pairsum32(((a0 + a1) + (a2 + a3)) + ((b0 + b1) + (b2 + b3)));
    }

    bf16x8 pb[4];
#pragma unroll
    for (int jh = 0; jh < 2; ++jh)
#pragma unroll
      for (int sub = 0; sub < 2; ++sub) {
        const f32x16& s = jh ? st1 : st0;
        int w01, w23, w45, w67;
        asm("v_cvt_pk_bf16_f32 %0, %1, %2" : "=v"(w01) : "v"(s[sub * 8 + 0]), "v"(s[sub * 8 + 1]));
        asm("v_cvt_pk_bf16_f32 %0, %1, %2" : "=v"(w23) : "v"(s[sub * 8 + 2]), "v"(s[sub * 8 + 3]));
        asm("v_cvt_pk_bf16_f32 %0, %1, %2" : "=v"(w45) : "v"(s[sub * 8 + 4]), "v"(s[sub * 8 + 5]));
        asm("v_cvt_pk_bf16_f32 %0, %1, %2" : "=v"(w67) : "v"(s[sub * 8 + 6]), "v"(s[sub * 8 + 7]));
        int d0, d1, d2, d3;
        plswap(w01, w45, d0, d2);
        plswap(w23, w67, d1, d3);
        union { int i[4]; bf16x8 v; } u;
        u.i[0] = d0; u.i[1] = d1; u.i[2] = d2; u.i[3] = d3;
        pb[jh * 2 + sub] = u.v;
      }

    __builtin_amdgcn_s_setprio(1);
#pragma unroll
    for (int js = 0; js < 4; ++js) {
      bf16x8 vf0 = *reinterpret_cast<const bf16x8*>(Vb + lq * 128 + swz(lq, js * 32 + lh * 16));
      o0 = __builtin_amdgcn_mfma_f32_32x32x16_bf16(vf0, pb[js], o0, 0, 0, 0);
    }
#pragma unroll
    for (int js = 0; js < 4; ++js) {
      bf16x8 vf1 = *reinterpret_cast<const bf16x8*>(Vb + (32 + lq) * 128 + swz(lq, js * 32 + lh * 16));
      o1 = __builtin_amdgcn_mfma_f32_32x32x16_bf16(vf1, pb[js], o1, 0, 0, 0);
    }
    __builtin_amdgcn_s_setprio(0);

    __syncthreads();
  }

  float* OL = reinterpret_cast<float*>(L + 32768);
  float2* MLx = reinterpret_cast<float2*>(L);
  __syncthreads();
  if (sg == 1) {
    MLx[w * 64 + lane] = make_float2(mrow, lrow);
#pragma unroll
    for (int r = 0; r < 16; ++r) OL[w * 2048 + r * 64 + lane] = o0[r];
#pragma unroll
    for (int r = 0; r < 16; ++r) OL[w * 2048 + (16 + r) * 64 + lane] = o1[r];
  }
  __syncthreads();
  if (sg == 0) {
    const float2 ml1 = MLx[w * 64 + lane];
    const float M = fmaxf(mrow, ml1.x);
    const float f0 = __builtin_amdgcn_exp2f(mrow - M);
    const float f1 = __builtin_amdgcn_exp2f(ml1.x - M);
    const float inv = 1.f / (f0 * lrow + f1 * ml1.y);
    const size_t orow = (baseRow + q0 + lq) * EMB + hoff;
#pragma unroll
    for (int g = 0; g < 4; ++g) {
      union { uint2 u2; bf16_t h[4]; } pu;
#pragma unroll
      for (int r = 0; r < 4; ++r)
        pu.h[r] = __float2bfloat16((f0 * o0[g * 4 + r] + f1 * OL[w * 2048 + (g * 4 + r) * 64 + lane]) * inv);
      *reinterpret_cast<uint2*>(Oout + orow + g * 8 + lh * 4) = pu.u2;
    }
#pragma unroll
    for (int g = 0; g < 4; ++g) {
      union { uint2 u2; bf16_t h[4]; } pu;
#pragma unroll
      for (int r = 0; r < 4; ++r)
        pu.h[r] = __float2bfloat16((f0 * o1[g * 4 + r] + f1 * OL[w * 2048 + (16 + g * 4 + r) * 64 + lane]) * inv);
      *reinterpret_cast<uint2*>(Oout + orow + 32 + g * 8 + lh * 4) = pu.u2;
    }
  }
}

// ---------------- row LayerNorm (1024 cols), f32 ----------------
__global__ __launch_bounds__(256) void ln_kernel(const float* __restrict__ Y,
                                                 const float* __restrict__ gamma,
                                                 const float* __restrict__ beta,
                                                 float* __restrict__ Out) {
  const int row = blockIdx.x;
  const int tid = threadIdx.x;
  const float4 v = reinterpret_cast<const float4*>(Y + (size_t)row * EMB)[tid];
  float s = v.x + v.y + v.z + v.w;
  float s2 = v.x * v.x + v.y * v.y + v.z * v.z + v.w * v.w;
#pragma unroll
  for (int m = 1; m < 64; m <<= 1) {
    s += __shfl_xor(s, m);
    s2 += __shfl_xor(s2, m);
  }
  __shared__ float ws[4], ws2[4];
  const int w = tid >> 6;
  if ((tid & 63) == 0) { ws[w] = s; ws2[w] = s2; }
  __syncthreads();
  s = ws[0] + ws[1] + ws[2] + ws[3];
  s2 = ws2[0] + ws2[1] + ws2[2] + ws2[3];
  const float mu = s * (1.f / EMB);
  const float var = s2 * (1.f / EMB) - mu * mu;
  const float rstd = rsqrtf(var + 1e-5f);
  const float4 g = reinterpret_cast<const float4*>(gamma)[tid];
  const float4 bt = reinterpret_cast<const float4*>(beta)[tid];
  float4 ov;
  ov.x = (v.x - mu) * rstd * g.x + bt.x;
  ov.y = (v.y - mu) * rstd * g.y + bt.y;
  ov.z = (v.z - mu) * rstd * g.z + bt.z;
  ov.w = (v.w - mu) * rstd * g.w + bt.w;
  reinterpret_cast<float4*>(Out + (size_t)row * EMB)[tid] = ov;
}

// ---------------- launch ----------------
extern "C" void kernel_launch(void* const* d_in, const int* in_sizes, int n_in,
                              void* d_out, int out_size, void* d_ws, size_t ws_size,
                              hipStream_t stream) {
  const float* x = (const float*)d_in[0];
  const float* Wq = (const float*)d_in[1];
  const float* Wk = (const float*)d_in[2];
  const float* Wv = (const float*)d_in[3];
  const float* Wo = (const float*)d_in[4];
  const float* gamma = (const float*)d_in[5];
  const float* beta = (const float*)d_in[6];
  float* out = (float*)d_out;

  char* p = (char*)d_ws;
  const size_t sz_rows_bf = (size_t)NROWS * EMB * sizeof(bf16_t);  // 8 MB
  const size_t sz_w_bf = (size_t)EMB * EMB * sizeof(bf16_t);       // 2 MB
  bf16_t* xb = (bf16_t*)p; p += sz_rows_bf;
  bf16_t* wqb = (bf16_t*)p; p += sz_w_bf;
  bf16_t* wkb = (bf16_t*)p; p += sz_w_bf;
  bf16_t* wvb = (bf16_t*)p; p += sz_w_bf;
  bf16_t* wob = (bf16_t*)p; p += sz_w_bf;
  bf16_t* q = (bf16_t*)p; p += sz_rows_bf;
  bf16_t* k = (bf16_t*)p; p += sz_rows_bf;
  bf16_t* vt = (bf16_t*)p; p += sz_rows_bf;   // [B*H*D][S] = 2048 x 2048
  bf16_t* attn = (bf16_t*)p; p += sz_rows_bf;
  float* y = (float*)q;  // alias: q/k dead after attn_kernel

  const int n4x = NROWS * EMB / 4;
  const int n4w = EMB * EMB / 4;
  cast_f32_to_bf16<<<n4x / 256, 256, 0, stream>>>(x, xb, n4x);
  cast4_w<<<dim3(n4w / 256, 1, 4), 256, 0, stream>>>(Wq, Wk, Wv, Wo, wqb, wkb, wvb, wob, n4w);

  gemm_qkv<<<dim3(EMB / 256, NROWS / 256, 3), 512, 0, stream>>>(xb, wqb, wkb, wvb, q, k, vt);

  attn_kernel<<<dim3(16, 16, BATCH), 512, 0, stream>>>(q, k, vt, attn);

  gemm_out<<<dim3(EMB / 128, NROWS / 128, 1), 256, 0, stream>>>(attn, wob, y, x);

  ln_kernel<<<NROWS, 256, 0, stream>>>(y, gamma, beta, out);
}

// Round 12
// 119.619 us; speedup vs baseline: 1.1199x; 1.1199x over previous
//
#include <hip/hip_runtime.h>
#include <hip/hip_bf16.h>
#include <cstdint>
#include <cstddef>

#define SEQ   2048
#define BATCH 2
#define NROWS 4096          // BATCH*SEQ
#define EMB   1024
#define NHEAD 16
#define HD    64
#define KVBLK 64
#define NTG   16            // kv tiles per in-block group (1024 keys / 64)

typedef __attribute__((ext_vector_type(8))) short bf16x8;
typedef __attribute__((ext_vector_type(4))) float f32x4;
typedef __attribute__((ext_vector_type(16))) float f32x16;
typedef __attribute__((ext_vector_type(2))) int i32x2;
typedef __hip_bfloat16 bf16_t;

__device__ __forceinline__ int swz(int row, int cb) { return cb ^ ((row & 7) << 4); }

__device__ __forceinline__ void plswap(int a, int b, int& ra, int& rb) {
#if __has_builtin(__builtin_amdgcn_permlane32_swap)
  i32x2 r = __builtin_amdgcn_permlane32_swap(a, b, false, false);
  ra = r[0]; rb = r[1];
#else
  const int pa = __shfl_xor(a, 32), pb = __shfl_xor(b, 32);
  const bool lo = (threadIdx.x & 63) < 32;
  ra = lo ? a : pb;
  rb = lo ? pa : b;
#endif
}
__device__ __forceinline__ float pairmax32(float v) {
  int r0, r1;
  plswap(__float_as_int(v), __float_as_int(v), r0, r1);
  return fmaxf(__int_as_float(r0), __int_as_float(r1));
}
__device__ __forceinline__ float pairsum32(float v) {
  int r0, r1;
  plswap(__float_as_int(v), __float_as_int(v), r0, r1);
  return __int_as_float(r0) + __int_as_float(r1);
}

// ---------------- merged casts f32 -> bf16 (x + 4 weights, one launch) ------
__global__ __launch_bounds__(256) void cast_all(const float* __restrict__ x,
                                                const float* __restrict__ a,
                                                const float* __restrict__ b,
                                                const float* __restrict__ c,
                                                const float* __restrict__ d,
                                                bf16_t* __restrict__ ox, bf16_t* __restrict__ oa,
                                                bf16_t* __restrict__ ob, bf16_t* __restrict__ oc,
                                                bf16_t* __restrict__ od) {
  const int z = blockIdx.z;
  const int n4w = EMB * EMB / 4;                 // 262144 = 1024 blocks x 256
  auto cvt = [](const float* in, bf16_t* out, int i) {
    float4 v = reinterpret_cast<const float4*>(in)[i];
    union { ushort4 u; bf16_t h[4]; } o;
    o.h[0] = __float2bfloat16(v.x);
    o.h[1] = __float2bfloat16(v.y);
    o.h[2] = __float2bfloat16(v.z);
    o.h[3] = __float2bfloat16(v.w);
    reinterpret_cast<ushort4*>(out)[i] = o.u;
  };
  const int base = blockIdx.x * 256 + threadIdx.x;
  if (z == 0) {
#pragma unroll
    for (int j = 0; j < 4; ++j) cvt(x, ox, j * n4w + base);   // 4*262144 = NROWS*EMB/4
  } else {
    const float* in = (z == 1) ? a : (z == 2) ? b : (z == 3) ? c : d;
    bf16_t* out = (z == 1) ? oa : (z == 2) ? ob : (z == 3) ? oc : od;
    cvt(in, out, base);
  }
}

// ---------------- 128x128 bf16 MFMA GEMM (m97 structure, 4 waves) ----------
// Round-9 version (proven). Y = A @ W^T.
// MODE 0: bf16 row-major out. MODE 2: bf16 out head-transposed to Vt.
template <int MODE>
__device__ __forceinline__ void gemm128_body(const bf16_t* __restrict__ A,
                                             const bf16_t* __restrict__ W,
                                             bf16_t* __restrict__ Ob) {
  __shared__ __align__(16) bf16_t As[128 * 32];
  __shared__ __align__(16) bf16_t Bs[128 * 32];
  const int tid = threadIdx.x;
  const int lane = tid & 63;
  const int wv = tid >> 6;
  const int wm = wv >> 1, wn = wv & 1;          // 2x2 waves, each owns 64x64
  const int brow = blockIdx.y * 128;
  const int bcol = blockIdx.x * 128;
  const int lr = lane & 15, lg = lane >> 4;

  f32x4 acc[4][4] = {};

  auto* As3 = (__attribute__((address_space(3))) char*)As;
  auto* Bs3 = (__attribute__((address_space(3))) char*)Bs;

  for (int k0 = 0; k0 < EMB; k0 += 32) {
    __syncthreads();
#pragma unroll
    for (int i = 0; i < 2; ++i) {
      const int chunk = i * 256 + tid;          // 0..511, 16B each
      const int row = chunk >> 2;               // tile row 0..127
      const int kc = (chunk & 3) * 8;           // k element 0/8/16/24
      const bf16_t* ga = A + (size_t)(brow + row) * EMB + k0 + kc;
      const bf16_t* gb = W + (size_t)(bcol + row) * EMB + k0 + kc;
      __builtin_amdgcn_global_load_lds((const __attribute__((address_space(1))) void*)ga,
                                       (__attribute__((address_space(3))) void*)(As3 + chunk * 16),
                                       16, 0, 0);
      __builtin_amdgcn_global_load_lds((const __attribute__((address_space(1))) void*)gb,
                                       (__attribute__((address_space(3))) void*)(Bs3 + chunk * 16),
                                       16, 0, 0);
    }
    __syncthreads();

    bf16x8 af[4], bfr[4];
#pragma unroll
    for (int m = 0; m < 4; ++m)
      af[m] = *reinterpret_cast<const bf16x8*>(&As[(wm * 64 + m * 16 + lr) * 32 + lg * 8]);
#pragma unroll
    for (int n = 0; n < 4; ++n)
      bfr[n] = *reinterpret_cast<const bf16x8*>(&Bs[(wn * 64 + n * 16 + lr) * 32 + lg * 8]);
#pragma unroll
    for (int m = 0; m < 4; ++m)
#pragma unroll
      for (int n = 0; n < 4; ++n)
        acc[m][n] = __builtin_amdgcn_mfma_f32_16x16x32_bf16(af[m], bfr[n], acc[m][n], 0, 0, 0);
  }

  const int r0 = brow + wm * 64;
  const int c0 = bcol + wn * 64;
#pragma unroll
  for (int m = 0; m < 4; ++m)
#pragma unroll
    for (int n = 0; n < 4; ++n) {
      if (MODE == 2) {
        const int row0 = r0 + m * 16 + lg * 4;
        const int col = c0 + n * 16 + lr;
        const size_t vt_row = (size_t)(row0 >> 11) * 1024 + col;
        const int s = row0 & 2047;
        union { uint2 u2; bf16_t h[4]; } pu;
#pragma unroll
        for (int r = 0; r < 4; ++r) pu.h[r] = __float2bfloat16(acc[m][n][r]);
        *reinterpret_cast<uint2*>(Ob + vt_row * SEQ + s) = pu.u2;
      } else {
#pragma unroll
        for (int r = 0; r < 4; ++r) {
          const int row = r0 + m * 16 + lg * 4 + r;
          const int col = c0 + n * 16 + lr;
          Ob[(size_t)row * EMB + col] = __float2bfloat16(acc[m][n][r]);
        }
      }
    }
}

__global__ __launch_bounds__(256) void gemm_qkv(const bf16_t* __restrict__ X,
                                                const bf16_t* __restrict__ Wq,
                                                const bf16_t* __restrict__ Wk,
                                                const bf16_t* __restrict__ Wv,
                                                bf16_t* __restrict__ Q,
                                                bf16_t* __restrict__ K,
                                                bf16_t* __restrict__ Vt) {
  if (blockIdx.z == 0)      gemm128_body<0>(X, Wq, Q);
  else if (blockIdx.z == 1) gemm128_body<0>(X, Wk, K);
  else                      gemm128_body<2>(X, Wv, Vt);
}

// ---------------- 128x64 bf16 GEMM + residual (gemm_out) --------------------
// Smaller N-tile -> 512 blocks = 2 blocks/CU = 2 waves/SIMD: one block's
// staging stall hides under the other's MFMA (R9 mechanism). acc[4][2]/wave.
__global__ __launch_bounds__(256) void gemm_out(const bf16_t* __restrict__ Attn,
                                                const bf16_t* __restrict__ Wo,
                                                float* __restrict__ Y,
                                                const float* __restrict__ X) {
  __shared__ __align__(16) bf16_t As[128 * 32];   // 8KB
  __shared__ __align__(16) bf16_t Bs[64 * 32];    // 4KB
  const int tid = threadIdx.x;
  const int lane = tid & 63;
  const int wv = tid >> 6;
  const int wm = wv >> 1, wn = wv & 1;            // 2x2 waves, each owns 64x32
  const int brow = blockIdx.y * 128;
  const int bcol = blockIdx.x * 64;
  const int lr = lane & 15, lg = lane >> 4;

  f32x4 acc[4][2] = {};

  auto* As3 = (__attribute__((address_space(3))) char*)As;
  auto* Bs3 = (__attribute__((address_space(3))) char*)Bs;

  for (int k0 = 0; k0 < EMB; k0 += 32) {
    __syncthreads();
#pragma unroll
    for (int i = 0; i < 2; ++i) {
      const int chunk = i * 256 + tid;            // A: 0..511
      const int row = chunk >> 2;
      const int kc = (chunk & 3) * 8;
      const bf16_t* ga = Attn + (size_t)(brow + row) * EMB + k0 + kc;
      __builtin_amdgcn_global_load_lds((const __attribute__((address_space(1))) void*)ga,
                                       (__attribute__((address_space(3))) void*)(As3 + chunk * 16),
                                       16, 0, 0);
    }
    {
      const int row = tid >> 2;                   // B: 0..63
      const int kc = (tid & 3) * 8;
      const bf16_t* gb = Wo + (size_t)(bcol + row) * EMB + k0 + kc;
      __builtin_amdgcn_global_load_lds((const __attribute__((address_space(1))) void*)gb,
                                       (__attribute__((address_space(3))) void*)(Bs3 + tid * 16),
                                       16, 0, 0);
    }
    __syncthreads();

    bf16x8 af[4], bfr[2];
#pragma unroll
    for (int m = 0; m < 4; ++m)
      af[m] = *reinterpret_cast<const bf16x8*>(&As[(wm * 64 + m * 16 + lr) * 32 + lg * 8]);
#pragma unroll
    for (int n = 0; n < 2; ++n)
      bfr[n] = *reinterpret_cast<const bf16x8*>(&Bs[(wn * 32 + n * 16 + lr) * 32 + lg * 8]);
#pragma unroll
    for (int m = 0; m < 4; ++m)
#pragma unroll
      for (int n = 0; n < 2; ++n)
        acc[m][n] = __builtin_amdgcn_mfma_f32_16x16x32_bf16(af[m], bfr[n], acc[m][n], 0, 0, 0);
  }

  const int r0 = brow + wm * 64;
  const int c0 = bcol + wn * 32;
#pragma unroll
  for (int m = 0; m < 4; ++m)
#pragma unroll
    for (int n = 0; n < 2; ++n)
#pragma unroll
      for (int r = 0; r < 4; ++r) {
        const int row = r0 + m * 16 + lg * 4 + r;
        const int col = c0 + n * 16 + lr;
        const size_t idx = (size_t)row * EMB + col;
        Y[idx] = acc[m][n][r] + X[idx];
      }
}

// ---------------- flash attention: 8 waves, in-block KV-split x2 (round-9) --
__global__ __launch_bounds__(512, 4) void attn_kernel(const bf16_t* __restrict__ Q,
                                                      const bf16_t* __restrict__ K,
                                                      const bf16_t* __restrict__ Vt,
                                                      bf16_t* __restrict__ Oout) {
  __shared__ __align__(16) char L[65536];

  const int tid = threadIdx.x;
  const int lane = tid & 63;
  const int wv = tid >> 6;
  const int w = wv & 3;
  const int sg = wv >> 2;
  const int lq = lane & 31;
  const int lh = lane >> 5;

  const int f = blockIdx.x + 16 * blockIdx.y + 256 * blockIdx.z;
  const int ww = (f & 7) * 64 + (f >> 3);
  const int qb = ww & 15;
  const int h = (ww >> 4) & 15;
  const int b = ww >> 8;

  const size_t baseRow = (size_t)b * SEQ;
  const int hoff = h * HD;
  const int q0 = qb * 128 + w * 32;

  const float qscale = 0.125f * 1.44269504f;
  bf16x8 qf[4];
#pragma unroll
  for (int ks = 0; ks < 4; ++ks) {
    bf16x8 t = *reinterpret_cast<const bf16x8*>(
        &Q[(baseRow + q0 + lq) * EMB + hoff + ks * 16 + lh * 8]);
    union { bf16x8 v; bf16_t h[8]; } u;
    u.v = t;
#pragma unroll
    for (int e = 0; e < 8; ++e)
      u.h[e] = __float2bfloat16(__bfloat162float(u.h[e]) * qscale);
    qf[ks] = u.v;
  }

  f32x16 o0 = {}, o1 = {};
  float mrow = -1e30f, lrow = 0.f;

  auto* L3 = (__attribute__((address_space(3))) char*)L;
  const int gbase = sg * 32768;

  const int stid = tid & 255;
  const int srow = stid >> 3;
  const int scb = swz(srow, (stid & 7) * 16) >> 1;
  const bf16_t* kp = K + (baseRow + sg * 1024 + srow) * EMB + hoff + scb;
  const bf16_t* vp = Vt + ((size_t)(b * 1024 + hoff) + srow) * SEQ + sg * 1024 + scb;

  auto stage = [&](int buf) {
#pragma unroll
    for (int i = 0; i < 2; ++i) {
      const int c = i * 256 + stid;
      __builtin_amdgcn_global_load_lds(
          (const __attribute__((address_space(1))) void*)(kp + i * 32 * EMB),
          (__attribute__((address_space(3))) void*)(L3 + gbase + buf * 8192 + c * 16), 16, 0, 0);
      __builtin_amdgcn_global_load_lds(
          (const __attribute__((address_space(1))) void*)(vp + i * 32 * SEQ),
          (__attribute__((address_space(3))) void*)(L3 + gbase + 16384 + buf * 8192 + c * 16), 16, 0, 0);
    }
    kp += KVBLK * EMB;
    vp += KVBLK;
  };

  stage(0);
  __syncthreads();

  for (int t = 0; t < NTG; ++t) {
    const int cur = t & 1;
    if (t + 1 < NTG) stage(cur ^ 1);

    const char* Kb = (const char*)L + gbase + cur * 8192;
    const char* Vb = (const char*)L + gbase + 16384 + cur * 8192;

    f32x16 st0 = {}, st1 = {};
    __builtin_amdgcn_s_setprio(1);
#pragma unroll
    for (int ks = 0; ks < 4; ++ks) {
      bf16x8 kf0 = *reinterpret_cast<const bf16x8*>(Kb + lq * 128 + swz(lq, ks * 32 + lh * 16));
      st0 = __builtin_amdgcn_mfma_f32_32x32x16_bf16(kf0, qf[ks], st0, 0, 0, 0);
    }
#pragma unroll
    for (int ks = 0; ks < 4; ++ks) {
      bf16x8 kf1 = *reinterpret_cast<const bf16x8*>(Kb + (32 + lq) * 128 + swz(lq, ks * 32 + lh * 16));
      st1 = __builtin_amdgcn_mfma_f32_32x32x16_bf16(kf1, qf[ks], st1, 0, 0, 0);
    }
    __builtin_amdgcn_s_setprio(0);

    float mx = -1e30f;
#pragma unroll
    for (int r = 0; r < 16; ++r) mx = fmaxf(mx, st0[r]);
#pragma unroll
    for (int r = 0; r < 16; ++r) mx = fmaxf(mx, st1[r]);
    mx = pairmax32(mx);

    if (!__all(mx - mrow <= 8.f)) {
      const float mnew = fmaxf(mrow, mx);
      const float al = __builtin_amdgcn_exp2f(mrow - mnew);
      mrow = mnew;
      lrow *= al;
#pragma unroll
      for (int r = 0; r < 16; ++r) o0[r] *= al;
#pragma unroll
      for (int r = 0; r < 16; ++r) o1[r] *= al;
    }

#pragma unroll
    for (int r = 0; r < 16; ++r) st0[r] = __builtin_amdgcn_exp2f(st0[r] - mrow);
#pragma unroll
    for (int r = 0; r < 16; ++r) st1[r] = __builtin_amdgcn_exp2f(st1[r] - mrow);
    {
      float a0 = (st0[0] + st0[1]) + (st0[2] + st0[3]);
      float a1 = (st0[4] + st0[5]) + (st0[6] + st0[7]);
      float a2 = (st0[8] + st0[9]) + (st0[10] + st0[11]);
      float a3 = (st0[12] + st0[13]) + (st0[14] + st0[15]);
      float b0 = (st1[0] + st1[1]) + (st1[2] + st1[3]);
      float b1 = (st1[4] + st1[5]) + (st1[6] + st1[7]);
      float b2 = (st1[8] + st1[9]) + (st1[10] + st1[11]);
      float b3 = (st1[12] + st1[13]) + (st1[14] + st1[15]);
      lrow += pairsum32(((a0 + a1) + (a2 + a3)) + ((b0 + b1) + (b2 + b3)));
    }

    bf16x8 pb[4];
#pragma unroll
    for (int jh = 0; jh < 2; ++jh)
#pragma unroll
      for (int sub = 0; sub < 2; ++sub) {
        const f32x16& s = jh ? st1 : st0;
        int w01, w23, w45, w67;
        asm("v_cvt_pk_bf16_f32 %0, %1, %2" : "=v"(w01) : "v"(s[sub * 8 + 0]), "v"(s[sub * 8 + 1]));
        asm("v_cvt_pk_bf16_f32 %0, %1, %2" : "=v"(w23) : "v"(s[sub * 8 + 2]), "v"(s[sub * 8 + 3]));
        asm("v_cvt_pk_bf16_f32 %0, %1, %2" : "=v"(w45) : "v"(s[sub * 8 + 4]), "v"(s[sub * 8 + 5]));
        asm("v_cvt_pk_bf16_f32 %0, %1, %2" : "=v"(w67) : "v"(s[sub * 8 + 6]), "v"(s[sub * 8 + 7]));
        int d0, d1, d2, d3;
        plswap(w01, w45, d0, d2);
        plswap(w23, w67, d1, d3);
        union { int i[4]; bf16x8 v; } u;
        u.i[0] = d0; u.i[1] = d1; u.i[2] = d2; u.i[3] = d3;
        pb[jh * 2 + sub] = u.v;
      }

    __builtin_amdgcn_s_setprio(1);
#pragma unroll
    for (int js = 0; js < 4; ++js) {
      bf16x8 vf0 = *reinterpret_cast<const bf16x8*>(Vb + lq * 128 + swz(lq, js * 32 + lh * 16));
      o0 = __builtin_amdgcn_mfma_f32_32x32x16_bf16(vf0, pb[js], o0, 0, 0, 0);
    }
#pragma unroll
    for (int js = 0; js < 4; ++js) {
      bf16x8 vf1 = *reinterpret_cast<const bf16x8*>(Vb + (32 + lq) * 128 + swz(lq, js * 32 + lh * 16));
      o1 = __builtin_amdgcn_mfma_f32_32x32x16_bf16(vf1, pb[js], o1, 0, 0, 0);
    }
    __builtin_amdgcn_s_setprio(0);

    __syncthreads();
  }

  float* OL = reinterpret_cast<float*>(L + 32768);
  float2* MLx = reinterpret_cast<float2*>(L);
  __syncthreads();
  if (sg == 1) {
    MLx[w * 64 + lane] = make_float2(mrow, lrow);
#pragma unroll
    for (int r = 0; r < 16; ++r) OL[w * 2048 + r * 64 + lane] = o0[r];
#pragma unroll
    for (int r = 0; r < 16; ++r) OL[w * 2048 + (16 + r) * 64 + lane] = o1[r];
  }
  __syncthreads();
  if (sg == 0) {
    const float2 ml1 = MLx[w * 64 + lane];
    const float M = fmaxf(mrow, ml1.x);
    const float f0 = __builtin_amdgcn_exp2f(mrow - M);
    const float f1 = __builtin_amdgcn_exp2f(ml1.x - M);
    const float inv = 1.f / (f0 * lrow + f1 * ml1.y);
    const size_t orow = (baseRow + q0 + lq) * EMB + hoff;
#pragma unroll
    for (int g = 0; g < 4; ++g) {
      union { uint2 u2; bf16_t h[4]; } pu;
#pragma unroll
      for (int r = 0; r < 4; ++r)
        pu.h[r] = __float2bfloat16((f0 * o0[g * 4 + r] + f1 * OL[w * 2048 + (g * 4 + r) * 64 + lane]) * inv);
      *reinterpret_cast<uint2*>(Oout + orow + g * 8 + lh * 4) = pu.u2;
    }
#pragma unroll
    for (int g = 0; g < 4; ++g) {
      union { uint2 u2; bf16_t h[4]; } pu;
#pragma unroll
      for (int r = 0; r < 4; ++r)
        pu.h[r] = __float2bfloat16((f0 * o1[g * 4 + r] + f1 * OL[w * 2048 + (16 + g * 4 + r) * 64 + lane]) * inv);
      *reinterpret_cast<uint2*>(Oout + orow + 32 + g * 8 + lh * 4) = pu.u2;
    }
  }
}

// ---------------- row LayerNorm (1024 cols), f32 ----------------
__global__ __launch_bounds__(256) void ln_kernel(const float* __restrict__ Y,
                                                 const float* __restrict__ gamma,
                                                 const float* __restrict__ beta,
                                                 float* __restrict__ Out) {
  const int row = blockIdx.x;
  const int tid = threadIdx.x;
  const float4 v = reinterpret_cast<const float4*>(Y + (size_t)row * EMB)[tid];
  float s = v.x + v.y + v.z + v.w;
  float s2 = v.x * v.x + v.y * v.y + v.z * v.z + v.w * v.w;
#pragma unroll
  for (int m = 1; m < 64; m <<= 1) {
    s += __shfl_xor(s, m);
    s2 += __shfl_xor(s2, m);
  }
  __shared__ float ws[4], ws2[4];
  const int w = tid >> 6;
  if ((tid & 63) == 0) { ws[w] = s; ws2[w] = s2; }
  __syncthreads();
  s = ws[0] + ws[1] + ws[2] + ws[3];
  s2 = ws2[0] + ws2[1] + ws2[2] + ws2[3];
  const float mu = s * (1.f / EMB);
  const float var = s2 * (1.f / EMB) - mu * mu;
  const float rstd = rsqrtf(var + 1e-5f);
  const float4 g = reinterpret_cast<const float4*>(gamma)[tid];
  const float4 bt = reinterpret_cast<const float4*>(beta)[tid];
  float4 ov;
  ov.x = (v.x - mu) * rstd * g.x + bt.x;
  ov.y = (v.y - mu) * rstd * g.y + bt.y;
  ov.z = (v.z - mu) * rstd * g.z + bt.z;
  ov.w = (v.w - mu) * rstd * g.w + bt.w;
  reinterpret_cast<float4*>(Out + (size_t)row * EMB)[tid] = ov;
}

// ---------------- launch ----------------
extern "C" void kernel_launch(void* const* d_in, const int* in_sizes, int n_in,
                              void* d_out, int out_size, void* d_ws, size_t ws_size,
                              hipStream_t stream) {
  const float* x = (const float*)d_in[0];
  const float* Wq = (const float*)d_in[1];
  const float* Wk = (const float*)d_in[2];
  const float* Wv = (const float*)d_in[3];
  const float* Wo = (const float*)d_in[4];
  const float* gamma = (const float*)d_in[5];
  const float* beta = (const float*)d_in[6];
  float* out = (float*)d_out;

  char* p = (char*)d_ws;
  const size_t sz_rows_bf = (size_t)NROWS * EMB * sizeof(bf16_t);  // 8 MB
  const size_t sz_w_bf = (size_t)EMB * EMB * sizeof(bf16_t);       // 2 MB
  bf16_t* xb = (bf16_t*)p; p += sz_rows_bf;
  bf16_t* wqb = (bf16_t*)p; p += sz_w_bf;
  bf16_t* wkb = (bf16_t*)p; p += sz_w_bf;
  bf16_t* wvb = (bf16_t*)p; p += sz_w_bf;
  bf16_t* wob = (bf16_t*)p; p += sz_w_bf;
  bf16_t* q = (bf16_t*)p; p += sz_rows_bf;
  bf16_t* k = (bf16_t*)p; p += sz_rows_bf;
  bf16_t* vt = (bf16_t*)p; p += sz_rows_bf;   // [B*H*D][S] = 2048 x 2048
  bf16_t* attn = (bf16_t*)p; p += sz_rows_bf;
  float* y = (float*)q;  // alias: q/k dead after attn_kernel

  const int n4w = EMB * EMB / 4;               // 262144 -> 1024 blocks
  cast_all<<<dim3(n4w / 256, 1, 5), 256, 0, stream>>>(x, Wq, Wk, Wv, Wo,
                                                      xb, wqb, wkb, wvb, wob);

  gemm_qkv<<<dim3(EMB / 128, NROWS / 128, 3), 256, 0, stream>>>(xb, wqb, wkb, wvb, q, k, vt);

  attn_kernel<<<dim3(16, 16, BATCH), 512, 0, stream>>>(q, k, vt, attn);

  gemm_out<<<dim3(EMB / 64, NROWS / 128, 1), 256, 0, stream>>>(attn, wob, y, x);

  ln_kernel<<<NROWS, 256, 0, stream>>>(y, gamma, beta, out);
}